// Round 6
// baseline (714.181 us; speedup 1.0000x reference)
//
#include <hip/hip_runtime.h>

#define D 64
#define NBMAX 512        // max buckets (nodes <= 131072)
#define TILE 8192        // edges per block in bucket passes

typedef unsigned int   uint;
typedef unsigned short ushort_t;
typedef __attribute__((ext_vector_type(8))) short bf16x8;
typedef __attribute__((ext_vector_type(4))) float f32x4;

__device__ __forceinline__ ushort_t f2bf(float f) {
    uint u = __float_as_uint(f);
    u += 0x7FFFu + ((u >> 16) & 1u);           // round-to-nearest-even
    return (ushort_t)(u >> 16);
}

// ---------------------------------------------------------------------------
// 0. x (fp32) -> bf16 packed, 8 elems/thread.
// ---------------------------------------------------------------------------
__global__ __launch_bounds__(256) void k_tobf16(
    const float4* __restrict__ x4, uint4* __restrict__ xb4, int n8)
{
    int t = blockIdx.x * blockDim.x + threadIdx.x;
    if (t >= n8) return;
    float4 a = x4[t * 2];
    float4 c = x4[t * 2 + 1];
    uint4 o;
    o.x = (uint)f2bf(a.x) | ((uint)f2bf(a.y) << 16);
    o.y = (uint)f2bf(a.z) | ((uint)f2bf(a.w) << 16);
    o.z = (uint)f2bf(c.x) | ((uint)f2bf(c.y) << 16);
    o.w = (uint)f2bf(c.z) | ((uint)f2bf(c.w) << 16);
    xb4[t] = o;
}

// ---------------------------------------------------------------------------
// A1. Per-block bucket histogram (bucket = dst>>8); reserve per-block ranges.
// ---------------------------------------------------------------------------
__global__ __launch_bounds__(256) void k_bhist(
    const int* __restrict__ dst, int* __restrict__ bucketCount,
    int* __restrict__ blockBase, int nb, int n_edges)
{
    __shared__ int hist[NBMAX];
    const int tid = threadIdx.x;
    for (int i = tid; i < nb; i += 256) hist[i] = 0;
    __syncthreads();

    const int e0 = blockIdx.x * TILE;
    const int n4 = n_edges >> 2;
    const int4* dst4 = (const int4*)dst;
#pragma unroll
    for (int k = 0; k < TILE / 1024; ++k) {
        int i4 = (e0 >> 2) + k * 256 + tid;
        if (i4 < n4) {
            int4 d = dst4[i4];
            atomicAdd(&hist[d.x >> 8], 1);
            atomicAdd(&hist[d.y >> 8], 1);
            atomicAdd(&hist[d.z >> 8], 1);
            atomicAdd(&hist[d.w >> 8], 1);
        }
    }
    if (blockIdx.x == gridDim.x - 1) {
        for (int e = (n4 << 2) + tid; e < n_edges; e += 256)
            atomicAdd(&hist[dst[e] >> 8], 1);
    }
    __syncthreads();
    for (int i = tid; i < nb; i += 256)
        blockBase[(size_t)blockIdx.x * nb + i] = atomicAdd(&bucketCount[i], hist[i]);
}

// ---------------------------------------------------------------------------
// A2. Scan bucket counts -> bucket bases (bucketBase[nb] = E).
// ---------------------------------------------------------------------------
__global__ __launch_bounds__(512) void k_bscan(
    const int* __restrict__ bucketCount, int* __restrict__ bucketBase, int nb)
{
    __shared__ int s[512];
    const int tid = threadIdx.x;
    int v = (tid < nb) ? bucketCount[tid] : 0;
    s[tid] = v;
    __syncthreads();
    for (int off = 1; off < 512; off <<= 1) {
        int t = (tid >= off) ? s[tid - off] : 0;
        __syncthreads();
        s[tid] += t;
        __syncthreads();
    }
    if (tid <= nb) bucketBase[tid] = s[tid] - v;
}

// ---------------------------------------------------------------------------
// A3. Scatter packed (src | dstLocal<<24) into bucket-grouped runs.
// ---------------------------------------------------------------------------
__global__ __launch_bounds__(256) void k_bscatter(
    const int* __restrict__ src, const int* __restrict__ dst,
    const int* __restrict__ bucketBase, const int* __restrict__ blockBase,
    int* __restrict__ packed, int nb, int n_edges)
{
    __shared__ int cur[NBMAX];
    const int tid = threadIdx.x;
    const int blk = blockIdx.x;
    for (int i = tid; i < nb; i += 256)
        cur[i] = bucketBase[i] + blockBase[(size_t)blk * nb + i];
    __syncthreads();

    const int e0 = blk * TILE;
    const int n4 = n_edges >> 2;
    const int4* src4 = (const int4*)src;
    const int4* dst4 = (const int4*)dst;
#pragma unroll
    for (int k = 0; k < TILE / 1024; ++k) {
        int i4 = (e0 >> 2) + k * 256 + tid;
        if (i4 < n4) {
            int4 sv = src4[i4];
            int4 dv = dst4[i4];
            int p;
            p = atomicAdd(&cur[dv.x >> 8], 1); packed[p] = sv.x | ((dv.x & 255) << 24);
            p = atomicAdd(&cur[dv.y >> 8], 1); packed[p] = sv.y | ((dv.y & 255) << 24);
            p = atomicAdd(&cur[dv.z >> 8], 1); packed[p] = sv.z | ((dv.z & 255) << 24);
            p = atomicAdd(&cur[dv.w >> 8], 1); packed[p] = sv.w | ((dv.w & 255) << 24);
        }
    }
    if (blk == gridDim.x - 1) {
        for (int e = (n4 << 2) + tid; e < n_edges; e += 256) {
            int p = atomicAdd(&cur[dst[e] >> 8], 1);
            packed[p] = src[e] | ((dst[e] & 255) << 24);
        }
    }
}

// ---------------------------------------------------------------------------
// B. LDS push-accumulate per bucket, feature-split: 2 blocks per bucket,
//    each owns 32 features (exactly one 64B line of each bf16 row, so the
//    halves don't duplicate HBM lines). accum row stride 33 dwords spreads
//    LDS atomic banks by (dstLocal + feat) % 32. Finalize: normalize with
//    (deg+1), add fp32 self term, pack h to bf16.
// ---------------------------------------------------------------------------
__global__ __launch_bounds__(1024) void k_push(
    const int* __restrict__ packed, const int* __restrict__ bucketBase,
    const uint4* __restrict__ xb4, const float4* __restrict__ x4,
    uint4* __restrict__ hB4, int n_nodes)
{
    __shared__ float accum[256][33];
    __shared__ int ldeg[256];

    const int tid = threadIdx.x;
    const int bucket = blockIdx.x >> 1;
    const int half = blockIdx.x & 1;

    {
        float* a = &accum[0][0];
        for (int i = tid; i < 256 * 33; i += 1024) a[i] = 0.0f;
        if (tid < 256) ldeg[tid] = 0;
    }
    __syncthreads();

    const int ebase = bucketBase[bucket];
    const int eend  = bucketBase[bucket + 1];
    const int slot = tid >> 2;          // 0..255 edge slot
    const int f8 = tid & 3;             // feats half*32 + f8*8 .. +7
    const int gbase = half * 4 + f8;    // uint4 index within bf16 row

    for (int i = ebase + slot; i < eend; i += 256) {
        int pk = packed[i];
        int s = pk & 0x00FFFFFF;
        int dl = ((uint)pk) >> 24;
        uint4 v = xb4[(size_t)s * 8 + gbase];
        float* a = &accum[dl][f8 * 8];
        atomicAdd(a + 0, __uint_as_float(v.x << 16));
        atomicAdd(a + 1, __uint_as_float(v.x & 0xFFFF0000u));
        atomicAdd(a + 2, __uint_as_float(v.y << 16));
        atomicAdd(a + 3, __uint_as_float(v.y & 0xFFFF0000u));
        atomicAdd(a + 4, __uint_as_float(v.z << 16));
        atomicAdd(a + 5, __uint_as_float(v.z & 0xFFFF0000u));
        atomicAdd(a + 6, __uint_as_float(v.w << 16));
        atomicAdd(a + 7, __uint_as_float(v.w & 0xFFFF0000u));
        if (f8 == 0) atomicAdd(&ldeg[dl], 1);
    }
    __syncthreads();

    const int nl = tid >> 2;
    const int node = (bucket << 8) + nl;
    if (node < n_nodes) {
        const int part = tid & 3;                 // feats half*32 + part*8 .. +7
        const float rinv = 1.0f / (float)(ldeg[nl] + 1);
        const float* ap = &accum[nl][part * 8];
        const int fbase = half * 8 + part * 2;    // float4 index in x row
        float4 xa = x4[(size_t)node * 16 + fbase];
        float4 xc = x4[(size_t)node * 16 + fbase + 1];
        float h0 = (ap[0] + xa.x) * rinv;
        float h1 = (ap[1] + xa.y) * rinv;
        float h2 = (ap[2] + xa.z) * rinv;
        float h3 = (ap[3] + xa.w) * rinv;
        float h4 = (ap[4] + xc.x) * rinv;
        float h5 = (ap[5] + xc.y) * rinv;
        float h6 = (ap[6] + xc.z) * rinv;
        float h7 = (ap[7] + xc.w) * rinv;
        uint4 o;
        o.x = (uint)f2bf(h0) | ((uint)f2bf(h1) << 16);
        o.y = (uint)f2bf(h2) | ((uint)f2bf(h3) << 16);
        o.z = (uint)f2bf(h4) | ((uint)f2bf(h5) << 16);
        o.w = (uint)f2bf(h6) | ((uint)f2bf(h7) << 16);
        hB4[(size_t)node * 8 + half * 4 + part] = o;
    }
}

// ---------------------------------------------------------------------------
// C. GEMM via MFMA: out[N][64] = h[N][64](bf16) @ W^T + b.
//    Per wave: 16-node tile, K=64 as 2x mfma_f32_16x16x32_bf16 per 16-wide
//    out-col tile (4 col tiles). B (W^T) fragments register-resident.
//    A/B share the same K-grouping so any shared K-permutation cancels;
//    C/D layout: col=lane&15, row=(lane>>4)*4+reg (HW-verified mapping).
// ---------------------------------------------------------------------------
__global__ __launch_bounds__(256) void k_gemm(
    const bf16x8* __restrict__ hB, const float* __restrict__ W,
    const float* __restrict__ b, float* __restrict__ out,
    int ntiles, int n_nodes)
{
    const int lane = threadIdx.x & 63;
    const int wv = threadIdx.x >> 6;
    const int m = lane & 15;        // A row / B col within tile
    const int g = lane >> 4;        // K lane-group (8 elems each)

    bf16x8 bf[4][2];
    float bias[4];
#pragma unroll
    for (int c = 0; c < 4; ++c) {
        bias[c] = b[c * 16 + m];
#pragma unroll
        for (int kh = 0; kh < 2; ++kh) {
            const float* wp = W + (size_t)(c * 16 + m) * 64 + kh * 32 + g * 8;
            float4 wa = *(const float4*)wp;
            float4 wb = *(const float4*)(wp + 4);
            bf16x8 f;
            f[0] = (short)f2bf(wa.x); f[1] = (short)f2bf(wa.y);
            f[2] = (short)f2bf(wa.z); f[3] = (short)f2bf(wa.w);
            f[4] = (short)f2bf(wb.x); f[5] = (short)f2bf(wb.y);
            f[6] = (short)f2bf(wb.z); f[7] = (short)f2bf(wb.w);
            bf[c][kh] = f;
        }
    }

    for (int t = blockIdx.x * 4 + wv; t < ntiles; t += gridDim.x * 4) {
        const int n0 = t * 16;
        const int arow = min(n0 + m, n_nodes - 1);
        bf16x8 a0 = hB[(size_t)arow * 8 + g];        // k = g*8 .. +7
        bf16x8 a1 = hB[(size_t)arow * 8 + 4 + g];    // k = 32 + g*8 .. +7
#pragma unroll
        for (int c = 0; c < 4; ++c) {
            f32x4 acc = {0.f, 0.f, 0.f, 0.f};
            acc = __builtin_amdgcn_mfma_f32_16x16x32_bf16(a0, bf[c][0], acc, 0, 0, 0);
            acc = __builtin_amdgcn_mfma_f32_16x16x32_bf16(a1, bf[c][1], acc, 0, 0, 0);
#pragma unroll
            for (int r = 0; r < 4; ++r) {
                int row = n0 + g * 4 + r;
                if (row < n_nodes)
                    out[(size_t)row * 64 + c * 16 + m] = acc[r] + bias[c];
            }
        }
    }
}

extern "C" void kernel_launch(void* const* d_in, const int* in_sizes, int n_in,
                              void* d_out, int out_size, void* d_ws, size_t ws_size,
                              hipStream_t stream)
{
    const float* x   = (const float*)d_in[0];
    const int*   src = (const int*)d_in[1];
    const int*   dst = (const int*)d_in[2];
    const float* W   = (const float*)d_in[3];
    const float* b   = (const float*)d_in[4];
    float* out = (float*)d_out;

    const int n_nodes = in_sizes[0] / D;
    const int n_edges = in_sizes[1];
    const int nb  = (n_nodes + 255) >> 8;            // buckets
    const int nbA = (n_edges + TILE - 1) / TILE;     // edge-pass blocks

    // Workspace: [xb N*64 bf16][hB N*64 bf16][bucketCount NBMAX]
    //            [bucketBase NBMAX+1][blockBase nbA*nb][packed E]
    ushort_t* xb = (ushort_t*)d_ws;
    uint4* hB = (uint4*)(xb + (size_t)n_nodes * D);
    int* bucketCount = (int*)((char*)hB + (size_t)n_nodes * D * 2);
    int* bucketBase  = bucketCount + NBMAX;
    int* blockBase   = bucketBase + NBMAX + 1;
    int* packed      = blockBase + (size_t)nbA * nb;

    hipMemsetAsync(bucketCount, 0, NBMAX * sizeof(int), stream);

    const int n8 = n_nodes * D / 8;
    k_tobf16  <<<(n8 + 255) / 256, 256, 0, stream>>>((const float4*)x, (uint4*)xb, n8);
    k_bhist   <<<nbA, 256, 0, stream>>>(dst, bucketCount, blockBase, nb, n_edges);
    k_bscan   <<<1,   512, 0, stream>>>(bucketCount, bucketBase, nb);
    k_bscatter<<<nbA, 256, 0, stream>>>(src, dst, bucketBase, blockBase, packed, nb, n_edges);
    k_push    <<<2 * nb, 1024, 0, stream>>>(packed, bucketBase, (const uint4*)xb,
                                            (const float4*)x, hB, n_nodes);
    const int ntiles = (n_nodes + 15) / 16;
    k_gemm    <<<512, 256, 0, stream>>>((const bf16x8*)hB, W, b, out, ntiles, n_nodes);
}

// Round 7
// 107.717 us; speedup vs baseline: 6.6302x; 6.6302x over previous
//
#include <hip/hip_runtime.h>

#define D 64
#define NBMAX 512        // max buckets (nodes <= 131072)
#define TILE 8192        // edges per block in bucket passes
#define CAP  8192        // LDS edge-staging capacity per bucket

typedef unsigned int   uint;
typedef unsigned short ushort_t;
typedef __attribute__((ext_vector_type(8))) short bf16x8;
typedef __attribute__((ext_vector_type(4))) float f32x4;

__device__ __forceinline__ ushort_t f2bf(float f) {
    uint u = __float_as_uint(f);
    u += 0x7FFFu + ((u >> 16) & 1u);           // round-to-nearest-even
    return (ushort_t)(u >> 16);
}

// ---------------------------------------------------------------------------
// 0. x (fp32) -> bf16 packed, 8 elems/thread.
// ---------------------------------------------------------------------------
__global__ __launch_bounds__(256) void k_tobf16(
    const float4* __restrict__ x4, uint4* __restrict__ xb4, int n8)
{
    int t = blockIdx.x * blockDim.x + threadIdx.x;
    if (t >= n8) return;
    float4 a = x4[t * 2];
    float4 c = x4[t * 2 + 1];
    uint4 o;
    o.x = (uint)f2bf(a.x) | ((uint)f2bf(a.y) << 16);
    o.y = (uint)f2bf(a.z) | ((uint)f2bf(a.w) << 16);
    o.z = (uint)f2bf(c.x) | ((uint)f2bf(c.y) << 16);
    o.w = (uint)f2bf(c.z) | ((uint)f2bf(c.w) << 16);
    xb4[t] = o;
}

// ---------------------------------------------------------------------------
// A1. Per-block bucket histogram (bucket = dst>>8); reserve per-block ranges.
// ---------------------------------------------------------------------------
__global__ __launch_bounds__(256) void k_bhist(
    const int* __restrict__ dst, int* __restrict__ bucketCount,
    int* __restrict__ blockBase, int nb, int n_edges)
{
    __shared__ int hist[NBMAX];
    const int tid = threadIdx.x;
    for (int i = tid; i < nb; i += 256) hist[i] = 0;
    __syncthreads();

    const int e0 = blockIdx.x * TILE;
    const int n4 = n_edges >> 2;
    const int4* dst4 = (const int4*)dst;
#pragma unroll
    for (int k = 0; k < TILE / 1024; ++k) {
        int i4 = (e0 >> 2) + k * 256 + tid;
        if (i4 < n4) {
            int4 d = dst4[i4];
            atomicAdd(&hist[d.x >> 8], 1);
            atomicAdd(&hist[d.y >> 8], 1);
            atomicAdd(&hist[d.z >> 8], 1);
            atomicAdd(&hist[d.w >> 8], 1);
        }
    }
    if (blockIdx.x == gridDim.x - 1) {
        for (int e = (n4 << 2) + tid; e < n_edges; e += 256)
            atomicAdd(&hist[dst[e] >> 8], 1);
    }
    __syncthreads();
    for (int i = tid; i < nb; i += 256)
        blockBase[(size_t)blockIdx.x * nb + i] = atomicAdd(&bucketCount[i], hist[i]);
}

// ---------------------------------------------------------------------------
// A2. Scan bucket counts -> bucket bases (bucketBase[nb] = E).
// ---------------------------------------------------------------------------
__global__ __launch_bounds__(512) void k_bscan(
    const int* __restrict__ bucketCount, int* __restrict__ bucketBase, int nb)
{
    __shared__ int s[512];
    const int tid = threadIdx.x;
    int v = (tid < nb) ? bucketCount[tid] : 0;
    s[tid] = v;
    __syncthreads();
    for (int off = 1; off < 512; off <<= 1) {
        int t = (tid >= off) ? s[tid - off] : 0;
        __syncthreads();
        s[tid] += t;
        __syncthreads();
    }
    if (tid <= nb) bucketBase[tid] = s[tid] - v;
}

// ---------------------------------------------------------------------------
// A3. Scatter packed (src | dstLocal<<24) into bucket-grouped runs.
// ---------------------------------------------------------------------------
__global__ __launch_bounds__(256) void k_bscatter(
    const int* __restrict__ src, const int* __restrict__ dst,
    const int* __restrict__ bucketBase, const int* __restrict__ blockBase,
    int* __restrict__ packed, int nb, int n_edges)
{
    __shared__ int cur[NBMAX];
    const int tid = threadIdx.x;
    const int blk = blockIdx.x;
    for (int i = tid; i < nb; i += 256)
        cur[i] = bucketBase[i] + blockBase[(size_t)blk * nb + i];
    __syncthreads();

    const int e0 = blk * TILE;
    const int n4 = n_edges >> 2;
    const int4* src4 = (const int4*)src;
    const int4* dst4 = (const int4*)dst;
#pragma unroll
    for (int k = 0; k < TILE / 1024; ++k) {
        int i4 = (e0 >> 2) + k * 256 + tid;
        if (i4 < n4) {
            int4 sv = src4[i4];
            int4 dv = dst4[i4];
            int p;
            p = atomicAdd(&cur[dv.x >> 8], 1); packed[p] = sv.x | ((dv.x & 255) << 24);
            p = atomicAdd(&cur[dv.y >> 8], 1); packed[p] = sv.y | ((dv.y & 255) << 24);
            p = atomicAdd(&cur[dv.z >> 8], 1); packed[p] = sv.z | ((dv.z & 255) << 24);
            p = atomicAdd(&cur[dv.w >> 8], 1); packed[p] = sv.w | ((dv.w & 255) << 24);
        }
    }
    if (blk == gridDim.x - 1) {
        for (int e = (n4 << 2) + tid; e < n_edges; e += 256) {
            int p = atomicAdd(&cur[dst[e] >> 8], 1);
            packed[p] = src[e] | ((dst[e] & 255) << 24);
        }
    }
}

// ---------------------------------------------------------------------------
// B. Fused per-bucket CSR build + gather-aggregate. One block per bucket
//    (1024 thr, 16 waves). Stage bucket edges in LDS, LDS hist+scan, scatter
//    esrc IN-PLACE into packed[] (staged copy makes this safe), then each
//    wave aggregates 16 nodes with the round-5 gather loop (8 edge-slots x
//    8 feature-eighths, 16 edges in flight) and writes h as bf16.
//    Fallback (ecnt > CAP, never hit for this input): masked full-scan.
// ---------------------------------------------------------------------------
__global__ __launch_bounds__(1024) void k_aggcsr(
    int* __restrict__ packed, const int* __restrict__ bucketBase,
    const uint4* __restrict__ xb4, const float4* __restrict__ x4,
    uint4* __restrict__ hB4, int n_nodes)
{
    __shared__ int lds_edges[CAP];
    __shared__ int ldeg[256];
    __shared__ int lofs[256];
    __shared__ int cur[256];

    const int tid = threadIdx.x;
    const int bucket = blockIdx.x;
    const int ebase = bucketBase[bucket];
    const int ecnt  = bucketBase[bucket + 1] - ebase;
    const bool fits = (ecnt <= CAP);

    if (tid < 256) ldeg[tid] = 0;
    __syncthreads();

    // Phase 1: stage + LDS degree histogram.
    if (fits) {
        for (int i = tid; i < ecnt; i += 1024) {
            int pk = packed[ebase + i];
            lds_edges[i] = pk;
            atomicAdd(&ldeg[((uint)pk) >> 24], 1);
        }
    } else {
        for (int i = tid; i < ecnt; i += 1024)
            atomicAdd(&ldeg[((uint)packed[ebase + i]) >> 24], 1);
    }
    __syncthreads();

    // Phase 2: exclusive scan of ldeg (threads 0..255; ldeg preserved).
    {
        int v = (tid < 256) ? ldeg[tid] : 0;
        if (tid < 256) lofs[tid] = v;
        __syncthreads();
        for (int off = 1; off < 256; off <<= 1) {
            int t = (tid < 256 && tid >= off) ? lofs[tid - off] : 0;
            __syncthreads();
            if (tid < 256) lofs[tid] += t;
            __syncthreads();
        }
        if (tid < 256) {
            int excl = lofs[tid] - v;
            lofs[tid] = excl;
            cur[tid] = excl;
        }
    }
    __syncthreads();

    // Phase 3: scatter esrc in-place into packed (fits path only).
    if (fits) {
        for (int i = tid; i < ecnt; i += 1024) {
            int pk = lds_edges[i];
            int pos = atomicAdd(&cur[((uint)pk) >> 24], 1);
            packed[ebase + pos] = pk & 0x00FFFFFF;
        }
    }
    __syncthreads();

    // Phase 4: aggregate. Wave w -> nodes w*16 .. w*16+15 of this bucket.
    const int wave = tid >> 6;
    const int lane = tid & 63;
    const int slot = lane >> 3;        // edge slot 0..7
    const int f8   = lane & 7;         // feature-eighth

#define CVLO(u) __uint_as_float((u) << 16)
#define CVHI(u) __uint_as_float((u) & 0xFFFF0000u)

    for (int j = 0; j < 16; ++j) {
        const int nl = wave * 16 + j;
        const int node = (bucket << 8) + nl;
        if (node >= n_nodes) break;
        const int cnt = ldeg[nl];

        float s[8];
#pragma unroll
        for (int i = 0; i < 8; ++i) s[i] = 0.0f;

        if (fits) {
            const int e0 = ebase + lofs[nl];
            for (int base = 0; base < cnt; base += 16) {
                int i0 = base + slot;
                int i1 = base + 8 + slot;
                float m0 = (i0 < cnt) ? 1.0f : 0.0f;
                float m1 = (i1 < cnt) ? 1.0f : 0.0f;
                int c0 = min(i0, cnt - 1);
                int c1 = min(i1, cnt - 1);
                int s0 = packed[e0 + c0];
                int s1 = packed[e0 + c1];
                uint4 v0 = xb4[(size_t)s0 * 8 + f8];
                uint4 v1 = xb4[(size_t)s1 * 8 + f8];
                s[0] = fmaf(m0, CVLO(v0.x), s[0]);
                s[1] = fmaf(m0, CVHI(v0.x), s[1]);
                s[2] = fmaf(m0, CVLO(v0.y), s[2]);
                s[3] = fmaf(m0, CVHI(v0.y), s[3]);
                s[4] = fmaf(m0, CVLO(v0.z), s[4]);
                s[5] = fmaf(m0, CVHI(v0.z), s[5]);
                s[6] = fmaf(m0, CVLO(v0.w), s[6]);
                s[7] = fmaf(m0, CVHI(v0.w), s[7]);
                s[0] = fmaf(m1, CVLO(v1.x), s[0]);
                s[1] = fmaf(m1, CVHI(v1.x), s[1]);
                s[2] = fmaf(m1, CVLO(v1.y), s[2]);
                s[3] = fmaf(m1, CVHI(v1.y), s[3]);
                s[4] = fmaf(m1, CVLO(v1.z), s[4]);
                s[5] = fmaf(m1, CVHI(v1.z), s[5]);
                s[6] = fmaf(m1, CVLO(v1.w), s[6]);
                s[7] = fmaf(m1, CVHI(v1.w), s[7]);
            }
        } else {
            // Slow-but-correct fallback: masked scan of the whole bucket.
            for (int base = 0; base < ecnt; base += 8) {
                int i0 = base + slot;
                int pk = packed[ebase + min(i0, ecnt - 1)];
                int dl = ((uint)pk) >> 24;
                float m0 = (i0 < ecnt && dl == nl) ? 1.0f : 0.0f;
                uint4 v0 = xb4[(size_t)(pk & 0x00FFFFFF) * 8 + f8];
                s[0] = fmaf(m0, CVLO(v0.x), s[0]);
                s[1] = fmaf(m0, CVHI(v0.x), s[1]);
                s[2] = fmaf(m0, CVLO(v0.y), s[2]);
                s[3] = fmaf(m0, CVHI(v0.y), s[3]);
                s[4] = fmaf(m0, CVLO(v0.z), s[4]);
                s[5] = fmaf(m0, CVHI(v0.z), s[5]);
                s[6] = fmaf(m0, CVLO(v0.w), s[6]);
                s[7] = fmaf(m0, CVHI(v0.w), s[7]);
            }
        }

        // Reduce across the 8 slots (lane bits 3..5).
#pragma unroll
        for (int i = 0; i < 8; ++i) {
            s[i] += __shfl_xor(s[i], 8, 64);
            s[i] += __shfl_xor(s[i], 16, 64);
            s[i] += __shfl_xor(s[i], 32, 64);
        }

        // Slot-0 lanes: fp32 self term, normalize, pack h -> bf16.
        if (slot == 0) {
            float4 xa = x4[(size_t)node * 16 + f8 * 2];
            float4 xc = x4[(size_t)node * 16 + f8 * 2 + 1];
            float rinv = 1.0f / (float)(cnt + 1);
            uint4 o;
            o.x = (uint)f2bf((s[0] + xa.x) * rinv) | ((uint)f2bf((s[1] + xa.y) * rinv) << 16);
            o.y = (uint)f2bf((s[2] + xa.z) * rinv) | ((uint)f2bf((s[3] + xa.w) * rinv) << 16);
            o.z = (uint)f2bf((s[4] + xc.x) * rinv) | ((uint)f2bf((s[5] + xc.y) * rinv) << 16);
            o.w = (uint)f2bf((s[6] + xc.z) * rinv) | ((uint)f2bf((s[7] + xc.w) * rinv) << 16);
            hB4[(size_t)node * 8 + f8] = o;
        }
    }
#undef CVLO
#undef CVHI
}

// ---------------------------------------------------------------------------
// C. GEMM via MFMA: out[N][64] = h[N][64](bf16) @ W^T + b.  (round-6 proven)
// ---------------------------------------------------------------------------
__global__ __launch_bounds__(256) void k_gemm(
    const bf16x8* __restrict__ hB, const float* __restrict__ W,
    const float* __restrict__ b, float* __restrict__ out,
    int ntiles, int n_nodes)
{
    const int lane = threadIdx.x & 63;
    const int wv = threadIdx.x >> 6;
    const int m = lane & 15;        // A row / B col within tile
    const int g = lane >> 4;        // K lane-group (8 elems each)

    bf16x8 bf[4][2];
    float bias[4];
#pragma unroll
    for (int c = 0; c < 4; ++c) {
        bias[c] = b[c * 16 + m];
#pragma unroll
        for (int kh = 0; kh < 2; ++kh) {
            const float* wp = W + (size_t)(c * 16 + m) * 64 + kh * 32 + g * 8;
            float4 wa = *(const float4*)wp;
            float4 wb = *(const float4*)(wp + 4);
            bf16x8 f;
            f[0] = (short)f2bf(wa.x); f[1] = (short)f2bf(wa.y);
            f[2] = (short)f2bf(wa.z); f[3] = (short)f2bf(wa.w);
            f[4] = (short)f2bf(wb.x); f[5] = (short)f2bf(wb.y);
            f[6] = (short)f2bf(wb.z); f[7] = (short)f2bf(wb.w);
            bf[c][kh] = f;
        }
    }

    for (int t = blockIdx.x * 4 + wv; t < ntiles; t += gridDim.x * 4) {
        const int n0 = t * 16;
        const int arow = min(n0 + m, n_nodes - 1);
        bf16x8 a0 = hB[(size_t)arow * 8 + g];        // k = g*8 .. +7
        bf16x8 a1 = hB[(size_t)arow * 8 + 4 + g];    // k = 32 + g*8 .. +7
#pragma unroll
        for (int c = 0; c < 4; ++c) {
            f32x4 acc = {0.f, 0.f, 0.f, 0.f};
            acc = __builtin_amdgcn_mfma_f32_16x16x32_bf16(a0, bf[c][0], acc, 0, 0, 0);
            acc = __builtin_amdgcn_mfma_f32_16x16x32_bf16(a1, bf[c][1], acc, 0, 0, 0);
#pragma unroll
            for (int r = 0; r < 4; ++r) {
                int row = n0 + g * 4 + r;
                if (row < n_nodes)
                    out[(size_t)row * 64 + c * 16 + m] = acc[r] + bias[c];
            }
        }
    }
}

extern "C" void kernel_launch(void* const* d_in, const int* in_sizes, int n_in,
                              void* d_out, int out_size, void* d_ws, size_t ws_size,
                              hipStream_t stream)
{
    const float* x   = (const float*)d_in[0];
    const int*   src = (const int*)d_in[1];
    const int*   dst = (const int*)d_in[2];
    const float* W   = (const float*)d_in[3];
    const float* b   = (const float*)d_in[4];
    float* out = (float*)d_out;

    const int n_nodes = in_sizes[0] / D;
    const int n_edges = in_sizes[1];
    const int nb  = (n_nodes + 255) >> 8;            // buckets
    const int nbA = (n_edges + TILE - 1) / TILE;     // edge-pass blocks

    // Workspace: [xb N*64 bf16][hB N*64 bf16][bucketCount NBMAX]
    //            [bucketBase NBMAX+1][blockBase nbA*nb][packed E]
    ushort_t* xb = (ushort_t*)d_ws;
    uint4* hB = (uint4*)(xb + (size_t)n_nodes * D);
    int* bucketCount = (int*)((char*)hB + (size_t)n_nodes * D * 2);
    int* bucketBase  = bucketCount + NBMAX;
    int* blockBase   = bucketBase + NBMAX + 1;
    int* packed      = blockBase + (size_t)nbA * nb;

    hipMemsetAsync(bucketCount, 0, NBMAX * sizeof(int), stream);

    const int n8 = n_nodes * D / 8;
    k_tobf16  <<<(n8 + 255) / 256, 256, 0, stream>>>((const float4*)x, (uint4*)xb, n8);
    k_bhist   <<<nbA, 256, 0, stream>>>(dst, bucketCount, blockBase, nb, n_edges);
    k_bscan   <<<1,   512, 0, stream>>>(bucketCount, bucketBase, nb);
    k_bscatter<<<nbA, 256, 0, stream>>>(src, dst, bucketBase, blockBase, packed, nb, n_edges);
    k_aggcsr  <<<nb, 1024, 0, stream>>>(packed, bucketBase, (const uint4*)xb,
                                        (const float4*)x, hB, n_nodes);
    const int ntiles = (n_nodes + 15) / 16;
    k_gemm    <<<512, 256, 0, stream>>>((const bf16x8*)hB, W, b, out, ntiles, n_nodes);
}

// Round 8
// 89.355 us; speedup vs baseline: 7.9926x; 1.2055x over previous
//
#include <hip/hip_runtime.h>

#define D 64
#define BSH 7            // bucket shift: 128 nodes per bucket
#define BSZ 128          // nodes per bucket
#define NBMAX 1024       // max buckets (nodes <= 131072)
#define TILE 8192        // edges per block in bucket passes
#define CAP  4096        // LDS edge-staging capacity per bucket (mean ~2048)

typedef unsigned int   uint;
typedef unsigned short ushort_t;
typedef __attribute__((ext_vector_type(8))) short bf16x8;
typedef __attribute__((ext_vector_type(4))) float f32x4;

__device__ __forceinline__ ushort_t f2bf(float f) {
    uint u = __float_as_uint(f);
    u += 0x7FFFu + ((u >> 16) & 1u);           // round-to-nearest-even
    return (ushort_t)(u >> 16);
}

// ---------------------------------------------------------------------------
// A1. Per-block bucket histogram (bucket = dst>>7); reserve per-block ranges.
//     Fused: also converts a slice of x (fp32) -> xb (bf16 packed).
// ---------------------------------------------------------------------------
__global__ __launch_bounds__(256) void k_bhist(
    const int* __restrict__ dst, int* __restrict__ bucketCount,
    int* __restrict__ blockBase, const float4* __restrict__ x4,
    uint4* __restrict__ xb4, int n8, int nb, int n_edges)
{
    __shared__ int hist[NBMAX];
    const int tid = threadIdx.x;
    for (int i = tid; i < nb; i += 256) hist[i] = 0;
    __syncthreads();

    // Fused bf16 conversion slice (independent of histogram work).
    {
        const int chunk = (n8 + gridDim.x - 1) / gridDim.x;
        const int lo = blockIdx.x * chunk;
        const int hi = min(n8, lo + chunk);
        for (int t = lo + tid; t < hi; t += 256) {
            float4 a = x4[t * 2];
            float4 c = x4[t * 2 + 1];
            uint4 o;
            o.x = (uint)f2bf(a.x) | ((uint)f2bf(a.y) << 16);
            o.y = (uint)f2bf(a.z) | ((uint)f2bf(a.w) << 16);
            o.z = (uint)f2bf(c.x) | ((uint)f2bf(c.y) << 16);
            o.w = (uint)f2bf(c.z) | ((uint)f2bf(c.w) << 16);
            xb4[t] = o;
        }
    }

    const int e0 = blockIdx.x * TILE;
    const int n4 = n_edges >> 2;
    const int4* dst4 = (const int4*)dst;
#pragma unroll
    for (int k = 0; k < TILE / 1024; ++k) {
        int i4 = (e0 >> 2) + k * 256 + tid;
        if (i4 < n4) {
            int4 d = dst4[i4];
            atomicAdd(&hist[d.x >> BSH], 1);
            atomicAdd(&hist[d.y >> BSH], 1);
            atomicAdd(&hist[d.z >> BSH], 1);
            atomicAdd(&hist[d.w >> BSH], 1);
        }
    }
    if (blockIdx.x == gridDim.x - 1) {
        for (int e = (n4 << 2) + tid; e < n_edges; e += 256)
            atomicAdd(&hist[dst[e] >> BSH], 1);
    }
    __syncthreads();
    for (int i = tid; i < nb; i += 256)
        blockBase[(size_t)blockIdx.x * nb + i] = atomicAdd(&bucketCount[i], hist[i]);
}

// ---------------------------------------------------------------------------
// A2. Scan bucket counts -> bucket bases (bucketBase[nb] = E). nb <= 1024.
// ---------------------------------------------------------------------------
__global__ __launch_bounds__(1024) void k_bscan(
    const int* __restrict__ bucketCount, int* __restrict__ bucketBase, int nb)
{
    __shared__ int s[1024];
    const int tid = threadIdx.x;
    int v = (tid < nb) ? bucketCount[tid] : 0;
    s[tid] = v;
    __syncthreads();
    for (int off = 1; off < 1024; off <<= 1) {
        int t = (tid >= off) ? s[tid - off] : 0;
        __syncthreads();
        s[tid] += t;
        __syncthreads();
    }
    if (tid <= nb) bucketBase[tid] = s[tid] - v;
}

// ---------------------------------------------------------------------------
// A3. Scatter packed (src | dstLocal<<24) into bucket-grouped runs.
// ---------------------------------------------------------------------------
__global__ __launch_bounds__(256) void k_bscatter(
    const int* __restrict__ src, const int* __restrict__ dst,
    const int* __restrict__ bucketBase, const int* __restrict__ blockBase,
    int* __restrict__ packed, int nb, int n_edges)
{
    __shared__ int cur[NBMAX];
    const int tid = threadIdx.x;
    const int blk = blockIdx.x;
    for (int i = tid; i < nb; i += 256)
        cur[i] = bucketBase[i] + blockBase[(size_t)blk * nb + i];
    __syncthreads();

    const int e0 = blk * TILE;
    const int n4 = n_edges >> 2;
    const int4* src4 = (const int4*)src;
    const int4* dst4 = (const int4*)dst;
#pragma unroll
    for (int k = 0; k < TILE / 1024; ++k) {
        int i4 = (e0 >> 2) + k * 256 + tid;
        if (i4 < n4) {
            int4 sv = src4[i4];
            int4 dv = dst4[i4];
            int p;
            p = atomicAdd(&cur[dv.x >> BSH], 1); packed[p] = sv.x | ((dv.x & (BSZ-1)) << 24);
            p = atomicAdd(&cur[dv.y >> BSH], 1); packed[p] = sv.y | ((dv.y & (BSZ-1)) << 24);
            p = atomicAdd(&cur[dv.z >> BSH], 1); packed[p] = sv.z | ((dv.z & (BSZ-1)) << 24);
            p = atomicAdd(&cur[dv.w >> BSH], 1); packed[p] = sv.w | ((dv.w & (BSZ-1)) << 24);
        }
    }
    if (blk == gridDim.x - 1) {
        for (int e = (n4 << 2) + tid; e < n_edges; e += 256) {
            int p = atomicAdd(&cur[dst[e] >> BSH], 1);
            packed[p] = src[e] | ((dst[e] & (BSZ-1)) << 24);
        }
    }
}

// ---------------------------------------------------------------------------
// B. Fused per-bucket CSR + aggregate. One block per 128-node bucket
//    (512 thr, 8 waves, ~35KB LDS -> 4 blocks/CU, 32 waves = full occupancy).
//    Stage edges in LDS, LDS hist+scan, sort esrc into LDS, then gather:
//    4 nodes x 16 lanes per wave-pass, each group walks ITS node's edges
//    serially (8B loads = 4 bf16 feats/lane, unroll 2). No cross-lane
//    reduce. h written as bf16 (coalesced 8B/lane).
// ---------------------------------------------------------------------------
__global__ __launch_bounds__(512) void k_aggcsr(
    const int* __restrict__ packed, const int* __restrict__ bucketBase,
    const uint2* __restrict__ xb2, const float4* __restrict__ x4,
    uint2* __restrict__ hB2, int n_nodes)
{
    __shared__ int raw[CAP];
    __shared__ int srt[CAP + 132];     // +pad so reads past ecnt stay in-bounds
    __shared__ int ldeg[BSZ];
    __shared__ int lofs[BSZ];
    __shared__ int cur[BSZ];

    const int tid = threadIdx.x;
    const int bucket = blockIdx.x;
    const int ebase = bucketBase[bucket];
    const int ecnt  = bucketBase[bucket + 1] - ebase;
    const bool fits = (ecnt <= CAP);
    const uint nmax = (uint)(n_nodes - 1);

    if (tid < BSZ) ldeg[tid] = 0;
    __syncthreads();

    // Phase 1: stage + degree histogram.
    if (fits) {
        for (int i = tid; i < ecnt; i += 512) {
            int pk = packed[ebase + i];
            raw[i] = pk;
            atomicAdd(&ldeg[((uint)pk) >> 24], 1);
        }
    } else {
        for (int i = tid; i < ecnt; i += 512)
            atomicAdd(&ldeg[((uint)packed[ebase + i]) >> 24], 1);
    }
    __syncthreads();

    // Phase 2: exclusive scan of ldeg (first 128 threads).
    {
        int v = 0;
        if (tid < BSZ) { v = ldeg[tid]; lofs[tid] = v; }
        __syncthreads();
        for (int off = 1; off < BSZ; off <<= 1) {
            int t = (tid < BSZ && tid >= off) ? lofs[tid - off] : 0;
            __syncthreads();
            if (tid < BSZ) lofs[tid] += t;
            __syncthreads();
        }
        if (tid < BSZ) { int e = lofs[tid] - v; lofs[tid] = e; cur[tid] = e; }
    }
    __syncthreads();

    // Phase 3: sort esrc into LDS (fits path).
    if (fits) {
        for (int i = tid; i < ecnt; i += 512) {
            int pk = raw[i];
            int pos = atomicAdd(&cur[((uint)pk) >> 24], 1);
            srt[pos] = pk & 0x00FFFFFF;
        }
    }
    __syncthreads();

    // Phase 4: gather. 8 waves x 4 passes x 4 node-groups (16 lanes each).
    const int wave = tid >> 6;
    const int lane = tid & 63;
    const int g    = lane >> 4;        // node group 0..3
    const int fq   = lane & 15;        // feats fq*4 .. fq*4+3

#define CVLO(u) __uint_as_float((u) << 16)
#define CVHI(u) __uint_as_float((u) & 0xFFFF0000u)

#pragma unroll
    for (int p = 0; p < 4; ++p) {
        const int nl = wave * 16 + p * 4 + g;
        const int node = (bucket << BSH) + nl;
        const bool valid = (node < n_nodes);
        const int cnt = valid ? ldeg[nl] : 0;
        const int eb  = valid ? lofs[nl] : 0;

        int cm = max(cnt, __shfl_xor(cnt, 16, 64));
        cm = max(cm, __shfl_xor(cm, 32, 64));

        float s0 = 0.f, s1 = 0.f, s2 = 0.f, s3 = 0.f;

        if (fits) {
            for (int i = 0; i < cm; i += 2) {
                int v0 = srt[eb + i];
                int v1 = srt[eb + i + 1];
                float m0 = (i < cnt) ? 1.0f : 0.0f;
                float m1 = (i + 1 < cnt) ? 1.0f : 0.0f;
                uint i0 = min((uint)v0, nmax);
                uint i1 = min((uint)v1, nmax);
                uint2 a = xb2[(size_t)i0 * 16 + fq];
                uint2 c = xb2[(size_t)i1 * 16 + fq];
                s0 = fmaf(m0, CVLO(a.x), s0);
                s1 = fmaf(m0, CVHI(a.x), s1);
                s2 = fmaf(m0, CVLO(a.y), s2);
                s3 = fmaf(m0, CVHI(a.y), s3);
                s0 = fmaf(m1, CVLO(c.x), s0);
                s1 = fmaf(m1, CVHI(c.x), s1);
                s2 = fmaf(m1, CVLO(c.y), s2);
                s3 = fmaf(m1, CVHI(c.y), s3);
            }
        } else {
            // Fallback (never hit for this input): masked scan of bucket.
            const int nlm = valid ? nl : -1;
            for (int i = 0; i < ecnt; ++i) {
                int pk = packed[ebase + i];
                float m0 = ((int)(((uint)pk) >> 24) == nlm) ? 1.0f : 0.0f;
                uint i0 = min((uint)(pk & 0x00FFFFFF), nmax);
                uint2 a = xb2[(size_t)i0 * 16 + fq];
                s0 = fmaf(m0, CVLO(a.x), s0);
                s1 = fmaf(m0, CVHI(a.x), s1);
                s2 = fmaf(m0, CVLO(a.y), s2);
                s3 = fmaf(m0, CVHI(a.y), s3);
            }
        }

        if (valid) {
            float rinv = 1.0f / (float)(cnt + 1);
            float4 xv = x4[(size_t)node * 16 + fq];
            float h0 = (s0 + xv.x) * rinv;
            float h1 = (s1 + xv.y) * rinv;
            float h2 = (s2 + xv.z) * rinv;
            float h3 = (s3 + xv.w) * rinv;
            uint2 o;
            o.x = (uint)f2bf(h0) | ((uint)f2bf(h1) << 16);
            o.y = (uint)f2bf(h2) | ((uint)f2bf(h3) << 16);
            hB2[(size_t)node * 16 + fq] = o;
        }
    }
#undef CVLO
#undef CVHI
}

// ---------------------------------------------------------------------------
// C. GEMM via MFMA: out[N][64] = h[N][64](bf16) @ W^T + b.  (proven r6/r7)
// ---------------------------------------------------------------------------
__global__ __launch_bounds__(256) void k_gemm(
    const bf16x8* __restrict__ hB, const float* __restrict__ W,
    const float* __restrict__ b, float* __restrict__ out,
    int ntiles, int n_nodes)
{
    const int lane = threadIdx.x & 63;
    const int wv = threadIdx.x >> 6;
    const int m = lane & 15;        // A row / B col within tile
    const int g = lane >> 4;        // K lane-group (8 elems each)

    bf16x8 bf[4][2];
    float bias[4];
#pragma unroll
    for (int c = 0; c < 4; ++c) {
        bias[c] = b[c * 16 + m];
#pragma unroll
        for (int kh = 0; kh < 2; ++kh) {
            const float* wp = W + (size_t)(c * 16 + m) * 64 + kh * 32 + g * 8;
            float4 wa = *(const float4*)wp;
            float4 wb = *(const float4*)(wp + 4);
            bf16x8 f;
            f[0] = (short)f2bf(wa.x); f[1] = (short)f2bf(wa.y);
            f[2] = (short)f2bf(wa.z); f[3] = (short)f2bf(wa.w);
            f[4] = (short)f2bf(wb.x); f[5] = (short)f2bf(wb.y);
            f[6] = (short)f2bf(wb.z); f[7] = (short)f2bf(wb.w);
            bf[c][kh] = f;
        }
    }

    for (int t = blockIdx.x * 4 + wv; t < ntiles; t += gridDim.x * 4) {
        const int n0 = t * 16;
        const int arow = min(n0 + m, n_nodes - 1);
        bf16x8 a0 = hB[(size_t)arow * 8 + g];        // k = g*8 .. +7
        bf16x8 a1 = hB[(size_t)arow * 8 + 4 + g];    // k = 32 + g*8 .. +7
#pragma unroll
        for (int c = 0; c < 4; ++c) {
            f32x4 acc = {0.f, 0.f, 0.f, 0.f};
            acc = __builtin_amdgcn_mfma_f32_16x16x32_bf16(a0, bf[c][0], acc, 0, 0, 0);
            acc = __builtin_amdgcn_mfma_f32_16x16x32_bf16(a1, bf[c][1], acc, 0, 0, 0);
#pragma unroll
            for (int r = 0; r < 4; ++r) {
                int row = n0 + g * 4 + r;
                if (row < n_nodes)
                    out[(size_t)row * 64 + c * 16 + m] = acc[r] + bias[c];
            }
        }
    }
}

extern "C" void kernel_launch(void* const* d_in, const int* in_sizes, int n_in,
                              void* d_out, int out_size, void* d_ws, size_t ws_size,
                              hipStream_t stream)
{
    const float* x   = (const float*)d_in[0];
    const int*   src = (const int*)d_in[1];
    const int*   dst = (const int*)d_in[2];
    const float* W   = (const float*)d_in[3];
    const float* b   = (const float*)d_in[4];
    float* out = (float*)d_out;

    const int n_nodes = in_sizes[0] / D;
    const int n_edges = in_sizes[1];
    const int nb  = (n_nodes + BSZ - 1) >> BSH;      // 128-node buckets
    const int nbA = (n_edges + TILE - 1) / TILE;     // edge-pass blocks

    // Workspace: [xb N*64 bf16][hB N*64 bf16][bucketCount NBMAX]
    //            [bucketBase NBMAX+1][blockBase nbA*nb][packed E]
    ushort_t* xb = (ushort_t*)d_ws;
    ushort_t* hB = xb + (size_t)n_nodes * D;
    int* bucketCount = (int*)(hB + (size_t)n_nodes * D);
    int* bucketBase  = bucketCount + NBMAX;
    int* blockBase   = bucketBase + NBMAX + 1;
    int* packed      = blockBase + (size_t)nbA * nb;

    hipMemsetAsync(bucketCount, 0, NBMAX * sizeof(int), stream);

    const int n8 = n_nodes * D / 8;
    k_bhist   <<<nbA, 256, 0, stream>>>(dst, bucketCount, blockBase,
                                        (const float4*)x, (uint4*)xb, n8, nb, n_edges);
    k_bscan   <<<1,  1024, 0, stream>>>(bucketCount, bucketBase, nb);
    k_bscatter<<<nbA, 256, 0, stream>>>(src, dst, bucketBase, blockBase, packed, nb, n_edges);
    k_aggcsr  <<<nb,  512, 0, stream>>>(packed, bucketBase, (const uint2*)xb,
                                        (const float4*)x, (uint2*)hB, n_nodes);
    const int ntiles = (n_nodes + 15) / 16;
    k_gemm    <<<512, 256, 0, stream>>>((const bf16x8*)hB, W, b, out, ntiles, n_nodes);
}

// Round 9
// 81.664 us; speedup vs baseline: 8.7454x; 1.0942x over previous
//
#include <hip/hip_runtime.h>

#define D 64
#define BSH 7            // bucket shift: 128 nodes per bucket
#define BSZ 128          // nodes per bucket
#define NBMAX 1024       // max buckets (nodes <= 131072)
#define TILE 8192        // edges per block in bucket passes
#define CAP  3072        // LDS edge-staging capacity per bucket (mean ~2046, 22 sigma)

typedef unsigned int   uint;
typedef unsigned short ushort_t;
typedef __attribute__((ext_vector_type(8))) short bf16x8;
typedef __attribute__((ext_vector_type(4))) float f32x4;

__device__ __forceinline__ ushort_t f2bf(float f) {
    uint u = __float_as_uint(f);
    u += 0x7FFFu + ((u >> 16) & 1u);           // round-to-nearest-even
    return (ushort_t)(u >> 16);
}

// ---------------------------------------------------------------------------
// A1. Per-block bucket histogram (bucket = dst>>7); reserve per-block ranges.
//     Fused: also converts a slice of x (fp32) -> xb (bf16 packed).
// ---------------------------------------------------------------------------
__global__ __launch_bounds__(256) void k_bhist(
    const int* __restrict__ dst, int* __restrict__ bucketCount,
    int* __restrict__ blockBase, const float4* __restrict__ x4,
    uint4* __restrict__ xb4, int n8, int nb, int n_edges)
{
    __shared__ int hist[NBMAX];
    const int tid = threadIdx.x;
    for (int i = tid; i < nb; i += 256) hist[i] = 0;
    __syncthreads();

    // Fused bf16 conversion slice (independent of histogram work).
    {
        const int chunk = (n8 + gridDim.x - 1) / gridDim.x;
        const int lo = blockIdx.x * chunk;
        const int hi = min(n8, lo + chunk);
        for (int t = lo + tid; t < hi; t += 256) {
            float4 a = x4[t * 2];
            float4 c = x4[t * 2 + 1];
            uint4 o;
            o.x = (uint)f2bf(a.x) | ((uint)f2bf(a.y) << 16);
            o.y = (uint)f2bf(a.z) | ((uint)f2bf(a.w) << 16);
            o.z = (uint)f2bf(c.x) | ((uint)f2bf(c.y) << 16);
            o.w = (uint)f2bf(c.z) | ((uint)f2bf(c.w) << 16);
            xb4[t] = o;
        }
    }

    const int e0 = blockIdx.x * TILE;
    const int n4 = n_edges >> 2;
    const int4* dst4 = (const int4*)dst;
#pragma unroll
    for (int k = 0; k < TILE / 1024; ++k) {
        int i4 = (e0 >> 2) + k * 256 + tid;
        if (i4 < n4) {
            int4 d = dst4[i4];
            atomicAdd(&hist[d.x >> BSH], 1);
            atomicAdd(&hist[d.y >> BSH], 1);
            atomicAdd(&hist[d.z >> BSH], 1);
            atomicAdd(&hist[d.w >> BSH], 1);
        }
    }
    if (blockIdx.x == gridDim.x - 1) {
        for (int e = (n4 << 2) + tid; e < n_edges; e += 256)
            atomicAdd(&hist[dst[e] >> BSH], 1);
    }
    __syncthreads();
    for (int i = tid; i < nb; i += 256)
        blockBase[(size_t)blockIdx.x * nb + i] = atomicAdd(&bucketCount[i], hist[i]);
}

// ---------------------------------------------------------------------------
// A2. Scan bucket counts -> bucket bases (bucketBase[nb] = E). nb <= 1024.
// ---------------------------------------------------------------------------
__global__ __launch_bounds__(1024) void k_bscan(
    const int* __restrict__ bucketCount, int* __restrict__ bucketBase, int nb)
{
    __shared__ int s[1024];
    const int tid = threadIdx.x;
    int v = (tid < nb) ? bucketCount[tid] : 0;
    s[tid] = v;
    __syncthreads();
    for (int off = 1; off < 1024; off <<= 1) {
        int t = (tid >= off) ? s[tid - off] : 0;
        __syncthreads();
        s[tid] += t;
        __syncthreads();
    }
    if (tid <= nb) bucketBase[tid] = s[tid] - v;
}

// ---------------------------------------------------------------------------
// A3. Scatter packed (src | dstLocal<<24) into bucket-grouped runs.
// ---------------------------------------------------------------------------
__global__ __launch_bounds__(256) void k_bscatter(
    const int* __restrict__ src, const int* __restrict__ dst,
    const int* __restrict__ bucketBase, const int* __restrict__ blockBase,
    int* __restrict__ packed, int nb, int n_edges)
{
    __shared__ int cur[NBMAX];
    const int tid = threadIdx.x;
    const int blk = blockIdx.x;
    for (int i = tid; i < nb; i += 256)
        cur[i] = bucketBase[i] + blockBase[(size_t)blk * nb + i];
    __syncthreads();

    const int e0 = blk * TILE;
    const int n4 = n_edges >> 2;
    const int4* src4 = (const int4*)src;
    const int4* dst4 = (const int4*)dst;
#pragma unroll
    for (int k = 0; k < TILE / 1024; ++k) {
        int i4 = (e0 >> 2) + k * 256 + tid;
        if (i4 < n4) {
            int4 sv = src4[i4];
            int4 dv = dst4[i4];
            int p;
            p = atomicAdd(&cur[dv.x >> BSH], 1); packed[p] = sv.x | ((dv.x & (BSZ-1)) << 24);
            p = atomicAdd(&cur[dv.y >> BSH], 1); packed[p] = sv.y | ((dv.y & (BSZ-1)) << 24);
            p = atomicAdd(&cur[dv.z >> BSH], 1); packed[p] = sv.z | ((dv.z & (BSZ-1)) << 24);
            p = atomicAdd(&cur[dv.w >> BSH], 1); packed[p] = sv.w | ((dv.w & (BSZ-1)) << 24);
        }
    }
    if (blk == gridDim.x - 1) {
        for (int e = (n4 << 2) + tid; e < n_edges; e += 256) {
            int p = atomicAdd(&cur[dst[e] >> BSH], 1);
            packed[p] = src[e] | ((dst[e] & (BSZ-1)) << 24);
        }
    }
}

// ---------------------------------------------------------------------------
// B. Fully fused per-bucket CSR + aggregate + MFMA GEMM + bias. One block
//    per 128-node bucket (512 thr, 8 waves, ~35KB LDS -> 4 blocks/CU).
//    Phases: stage W->LDS(bf16,swz) | stage edges + hist | scan | LDS sort |
//    gather (4 nodes x 16 lanes/wave, unroll 4, self-term from xb) keeping h
//    in registers | barrier, restage h into reused pool LDS (swz) | per-wave
//    16x16x32 MFMA x8 -> out fp32 directly. No hB round-trip, no k_gemm.
// ---------------------------------------------------------------------------
__global__ __launch_bounds__(512, 8) void k_aggcsr(
    const int* __restrict__ packed, const int* __restrict__ bucketBase,
    const uint2* __restrict__ xb2, const float* __restrict__ W,
    const float* __restrict__ bvec, float* __restrict__ out, int n_nodes)
{
    __shared__ int pool[2 * CAP + 128];   // raw | srt(+pad); reused for h-staging
    __shared__ ushort_t Wl[64 * 64];      // bf16 W, XOR-swizzled rows
    __shared__ int ldeg[BSZ];
    __shared__ int lofs[BSZ];
    __shared__ int cur[BSZ];

    int* raw = pool;
    int* srt = pool + CAP;

    const int tid = threadIdx.x;
    const int bucket = blockIdx.x;
    const int ebase = bucketBase[bucket];
    const int ecnt  = bucketBase[bucket + 1] - ebase;
    const bool fits = (ecnt <= CAP);
    const uint nmax = (uint)(n_nodes - 1);

    // Phase 0: stage W (fp32 -> bf16) into LDS with byte ^= (row&7)<<4 swizzle.
    {
        const int o = tid >> 3;            // row 0..63
        const int j = (tid & 7) * 8;       // col 0..56
        const float* wp = W + o * 64 + j;
        float4 wa = *(const float4*)wp;
        float4 wb = *(const float4*)(wp + 4);
        uint4 w4;
        w4.x = (uint)f2bf(wa.x) | ((uint)f2bf(wa.y) << 16);
        w4.y = (uint)f2bf(wa.z) | ((uint)f2bf(wa.w) << 16);
        w4.z = (uint)f2bf(wb.x) | ((uint)f2bf(wb.y) << 16);
        w4.w = (uint)f2bf(wb.z) | ((uint)f2bf(wb.w) << 16);
        *(uint4*)((char*)Wl + o * 128 + ((j * 2) ^ ((o & 7) << 4))) = w4;
    }
    if (tid < BSZ) ldeg[tid] = 0;
    __syncthreads();

    // Phase 1: stage edges + degree histogram.
    if (fits) {
        for (int i = tid; i < ecnt; i += 512) {
            int pk = packed[ebase + i];
            raw[i] = pk;
            atomicAdd(&ldeg[((uint)pk) >> 24], 1);
        }
    } else {
        for (int i = tid; i < ecnt; i += 512)
            atomicAdd(&ldeg[((uint)packed[ebase + i]) >> 24], 1);
    }
    __syncthreads();

    // Phase 2: exclusive scan of ldeg (first 128 threads).
    {
        int v = 0;
        if (tid < BSZ) { v = ldeg[tid]; lofs[tid] = v; }
        __syncthreads();
        for (int off = 1; off < BSZ; off <<= 1) {
            int t = (tid < BSZ && tid >= off) ? lofs[tid - off] : 0;
            __syncthreads();
            if (tid < BSZ) lofs[tid] += t;
            __syncthreads();
        }
        if (tid < BSZ) { int e = lofs[tid] - v; lofs[tid] = e; cur[tid] = e; }
    }
    __syncthreads();

    // Phase 3: sort esrc into LDS (fits path).
    if (fits) {
        for (int i = tid; i < ecnt; i += 512) {
            int pk = raw[i];
            int pos = atomicAdd(&cur[((uint)pk) >> 24], 1);
            srt[pos] = pk & 0x00FFFFFF;
        }
    }
    __syncthreads();

    // Phase 4: gather. Wave w owns nodes w*16..w*16+15 (4 passes x 4 groups).
    const int wave = tid >> 6;
    const int lane = tid & 63;
    const int g    = lane >> 4;        // node group 0..3
    const int fq   = lane & 15;        // feats fq*4 .. fq*4+3

#define CVLO(u) __uint_as_float((u) << 16)
#define CVHI(u) __uint_as_float((u) & 0xFFFF0000u)

    uint2 hreg[4];
#pragma unroll
    for (int p = 0; p < 4; ++p) { hreg[p].x = 0u; hreg[p].y = 0u; }

#pragma unroll
    for (int p = 0; p < 4; ++p) {
        const int nl = wave * 16 + p * 4 + g;
        const int node = (bucket << BSH) + nl;
        const bool valid = (node < n_nodes);
        const int cnt = valid ? ldeg[nl] : 0;
        const int eb  = valid ? lofs[nl] : 0;

        int cm = max(cnt, __shfl_xor(cnt, 16, 64));
        cm = max(cm, __shfl_xor(cm, 32, 64));

        float s0 = 0.f, s1 = 0.f, s2 = 0.f, s3 = 0.f;

        if (fits) {
            for (int i = 0; i < cm; i += 4) {
                int v0 = srt[eb + i];
                int v1 = srt[eb + i + 1];
                int v2 = srt[eb + i + 2];
                int v3 = srt[eb + i + 3];
                float m0 = (i     < cnt) ? 1.0f : 0.0f;
                float m1 = (i + 1 < cnt) ? 1.0f : 0.0f;
                float m2 = (i + 2 < cnt) ? 1.0f : 0.0f;
                float m3 = (i + 3 < cnt) ? 1.0f : 0.0f;
                uint2 A0 = xb2[(size_t)min((uint)v0, nmax) * 16 + fq];
                uint2 A1 = xb2[(size_t)min((uint)v1, nmax) * 16 + fq];
                uint2 A2 = xb2[(size_t)min((uint)v2, nmax) * 16 + fq];
                uint2 A3 = xb2[(size_t)min((uint)v3, nmax) * 16 + fq];
                s0 = fmaf(m0, CVLO(A0.x), s0);
                s1 = fmaf(m0, CVHI(A0.x), s1);
                s2 = fmaf(m0, CVLO(A0.y), s2);
                s3 = fmaf(m0, CVHI(A0.y), s3);
                s0 = fmaf(m1, CVLO(A1.x), s0);
                s1 = fmaf(m1, CVHI(A1.x), s1);
                s2 = fmaf(m1, CVLO(A1.y), s2);
                s3 = fmaf(m1, CVHI(A1.y), s3);
                s0 = fmaf(m2, CVLO(A2.x), s0);
                s1 = fmaf(m2, CVHI(A2.x), s1);
                s2 = fmaf(m2, CVLO(A2.y), s2);
                s3 = fmaf(m2, CVHI(A2.y), s3);
                s0 = fmaf(m3, CVLO(A3.x), s0);
                s1 = fmaf(m3, CVHI(A3.x), s1);
                s2 = fmaf(m3, CVLO(A3.y), s2);
                s3 = fmaf(m3, CVHI(A3.y), s3);
            }
        } else {
            // Fallback (never hit for this input): masked scan of bucket.
            const int nlm = valid ? nl : -1;
            for (int i = 0; i < ecnt; ++i) {
                int pk = packed[ebase + i];
                float m0 = ((int)(((uint)pk) >> 24) == nlm) ? 1.0f : 0.0f;
                uint2 A0 = xb2[(size_t)min((uint)(pk & 0x00FFFFFF), nmax) * 16 + fq];
                s0 = fmaf(m0, CVLO(A0.x), s0);
                s1 = fmaf(m0, CVHI(A0.x), s1);
                s2 = fmaf(m0, CVLO(A0.y), s2);
                s3 = fmaf(m0, CVHI(A0.y), s3);
            }
        }

        if (valid) {
            uint2 xv = xb2[(size_t)node * 16 + fq];   // bf16 self term
            float rinv = 1.0f / (float)(cnt + 1);
            float h0 = (s0 + CVLO(xv.x)) * rinv;
            float h1 = (s1 + CVHI(xv.x)) * rinv;
            float h2 = (s2 + CVLO(xv.y)) * rinv;
            float h3 = (s3 + CVHI(xv.y)) * rinv;
            hreg[p].x = (uint)f2bf(h0) | ((uint)f2bf(h1) << 16);
            hreg[p].y = (uint)f2bf(h2) | ((uint)f2bf(h3) << 16);
        }
    }
#undef CVLO
#undef CVHI

    // All waves done with srt/raw -> reuse pool as h staging (16 KB needed).
    __syncthreads();

    char* hwb = (char*)pool + wave * 2048;   // this wave's 16x64 bf16 tile
#pragma unroll
    for (int p = 0; p < 4; ++p) {
        int nl = p * 4 + g;                  // row within wave tile
        *(uint2*)(hwb + nl * 128 + ((fq * 8) ^ ((nl & 7) << 4))) = hreg[p];
    }

    // MFMA epilogue (proven k_gemm fragment mapping; A from wave-local LDS).
    const int m  = lane & 15;
    const int kg = lane >> 4;
    bf16x8 a0 = *(const bf16x8*)(hwb + m * 128 + (((kg * 16)     ) ^ ((m & 7) << 4)));
    bf16x8 a1 = *(const bf16x8*)(hwb + m * 128 + (((64 + kg * 16)) ^ ((m & 7) << 4)));

    const int node0 = (bucket << BSH) + wave * 16;
#pragma unroll
    for (int c = 0; c < 4; ++c) {
        const int o = c * 16 + m;
        bf16x8 b0 = *(const bf16x8*)((char*)Wl + o * 128 + (((kg * 16)     ) ^ ((o & 7) << 4)));
        bf16x8 b1 = *(const bf16x8*)((char*)Wl + o * 128 + (((64 + kg * 16)) ^ ((o & 7) << 4)));
        f32x4 acc = {0.f, 0.f, 0.f, 0.f};
        acc = __builtin_amdgcn_mfma_f32_16x16x32_bf16(a0, b0, acc, 0, 0, 0);
        acc = __builtin_amdgcn_mfma_f32_16x16x32_bf16(a1, b1, acc, 0, 0, 0);
        const float bias = bvec[o];
#pragma unroll
        for (int r = 0; r < 4; ++r) {
            int row = node0 + kg * 4 + r;
            if (row < n_nodes)
                out[(size_t)row * 64 + o] = acc[r] + bias;
        }
    }
}

extern "C" void kernel_launch(void* const* d_in, const int* in_sizes, int n_in,
                              void* d_out, int out_size, void* d_ws, size_t ws_size,
                              hipStream_t stream)
{
    const float* x   = (const float*)d_in[0];
    const int*   src = (const int*)d_in[1];
    const int*   dst = (const int*)d_in[2];
    const float* W   = (const float*)d_in[3];
    const float* b   = (const float*)d_in[4];
    float* out = (float*)d_out;

    const int n_nodes = in_sizes[0] / D;
    const int n_edges = in_sizes[1];
    const int nb  = (n_nodes + BSZ - 1) >> BSH;      // 128-node buckets
    const int nbA = (n_edges + TILE - 1) / TILE;     // edge-pass blocks

    // Workspace: [xb N*64 bf16][bucketCount NBMAX][bucketBase NBMAX+1]
    //            [blockBase nbA*nb][packed E]
    ushort_t* xb = (ushort_t*)d_ws;
    int* bucketCount = (int*)(xb + (size_t)n_nodes * D);
    int* bucketBase  = bucketCount + NBMAX;
    int* blockBase   = bucketBase + NBMAX + 1;
    int* packed      = blockBase + (size_t)nbA * nb;

    hipMemsetAsync(bucketCount, 0, NBMAX * sizeof(int), stream);

    const int n8 = n_nodes * D / 8;
    k_bhist   <<<nbA, 256, 0, stream>>>(dst, bucketCount, blockBase,
                                        (const float4*)x, (uint4*)xb, n8, nb, n_edges);
    k_bscan   <<<1,  1024, 0, stream>>>(bucketCount, bucketBase, nb);
    k_bscatter<<<nbA, 256, 0, stream>>>(src, dst, bucketBase, blockBase, packed, nb, n_edges);
    k_aggcsr  <<<nb,  512, 0, stream>>>(packed, bucketBase, (const uint2*)xb,
                                        W, b, out, n_nodes);
}